// Round 15
// baseline (96.528 us; speedup 1.0000x reference)
//
#include <hip/hip_runtime.h>

#define SS 4096
#define CC 128
#define BB 32
#define KW 25
#define PADW 12
#define CH 32                   // rows per chunk
#define SROWS (CH + KW - 1)     // 56 staged rows
#define CPB 8                   // chunks per block
#define ROWSPB (CH * CPB)       // 256 rows per block
#define NSTRIP (SS / ROWSPB)    // 16 strips per batch
#define NSERIES (BB * CC)       // 4096
#define STAGE_F4 (SROWS * CC / 4)   // 1792 float4 = 28 KiB per buffer

typedef float f4v __attribute__((ext_vector_type(4)));
typedef float f2v __attribute__((ext_vector_type(2)));

// ---------------- KB: single kernel: trend + speculative seasonal + stats ----
// 512 blocks x 512 threads (2 blocks/CU), persistent over 8 32-row chunks,
// double-buffered 28 KiB stages, halo LDS->LDS. Last block per batch (atomic
// ticket) folds the 16 strip-partials, computes cond, fixes up cond-false
// series (none for N(0,1) input).
__global__ __launch_bounds__(512, 4)
void kb_pass(const float* __restrict__ x, float* __restrict__ trend,
             float* __restrict__ seasonal, float* __restrict__ stats,
             int* __restrict__ cnt) {
    __shared__ f4v stage[2][STAGE_F4];        // 56 KiB (reused for sred)
    __shared__ float fin[7][128];             // finalize sums
    __shared__ int ticket_s, nf;
    __shared__ int flist[128];

    const int blk = blockIdx.x;               // 0..511
    const int b = blk >> 4;                   // batch
    const int st = blk & 15;                  // strip
    const int s0 = st * ROWSPB;
    const int tid = threadIdx.x;
    const int cp = tid & 63;                  // channel pair
    const int rg = tid >> 6;                  // row group 0..7 (4 rows/chunk)
    const float* __restrict__ xb = x + (size_t)b * SS * CC;
    f2v* __restrict__ tb = (f2v*)(trend + (size_t)b * SS * CC);
    f2v* __restrict__ sv = (f2v*)(seasonal + (size_t)b * SS * CC);

    // ---- prologue: stage rows s0-12 .. s0+43 into buffer 0 ----
    {
        const int sbase = s0 - PADW;
        #pragma unroll
        for (int t = 0; t < 4; ++t) {
            const int idx = t * 512 + tid;
            if (idx < STAGE_F4) {
                const int srow = sbase + (idx >> 5);
                const int crow = srow < 0 ? 0 : (srow >= SS ? SS - 1 : srow);
                f4v v = *(const f4v*)(xb + (size_t)crow * CC + ((idx & 31) << 2));
                if (srow < 0 || srow >= SS) v = (f4v){0.f, 0.f, 0.f, 0.f};
                stage[0][idx] = v;
            }
        }
    }

    f4v vals[2];
    auto issue = [&](int c) {                 // 32 new rows (staged 24..55)
        const int sbase = s0 + c * CH - PADW;
        #pragma unroll
        for (int t = 0; t < 2; ++t) {
            const int nidx = t * 512 + tid;   // 0..1023
            const int srow = sbase + 24 + (nidx >> 5);
            const int crow = srow >= SS ? SS - 1 : srow;  // never <0 for c>=1
            vals[t] = *(const f4v*)(xb + (size_t)crow * CC + ((nidx & 31) << 2));
        }
    };
    auto commit = [&](int c, int buf) {
        // halo: new staged rows 0..23 = old staged rows 32..55
        const f2v* src = (const f2v*)stage[buf ^ 1];
        f2v* dst = (f2v*)stage[buf];
        #pragma unroll
        for (int t = 0; t < 3; ++t) {
            const int hidx = t * 512 + tid;   // 0..1535
            dst[hidx] = src[CH * 64 + hidx];
        }
        const int sbase = s0 + c * CH - PADW;
        #pragma unroll
        for (int t = 0; t < 2; ++t) {
            const int nidx = t * 512 + tid;
            const int srow = sbase + 24 + (nidx >> 5);
            f4v w = vals[t];
            if (srow >= SS) w = (f4v){0.f, 0.f, 0.f, 0.f};
            stage[buf][768 + nidx] = w;       // 24 rows * 32 f4 = 768
        }
    };

    f2v Sx_e = {0,0}, Sx_o = {0,0}, Sx2 = {0,0};
    f2v St_e = {0,0}, St_o = {0,0}, St2 = {0,0}, Sxt = {0,0};

    for (int c = 0; c < CPB; ++c) {
        __syncthreads();                      // stage[c&1] ready
        const int cur = c & 1;
        if (c + 1 < CPB) issue(c + 1);        // overlap loads with compute

        const int Rb = s0 + c * CH;
        const int r0 = rg * 4;                // local row base (even)
        const f2v* stg = (const f2v*)stage[cur];

        f2v win[KW];
        #pragma unroll
        for (int j = 0; j < KW; ++j) win[j] = stg[(r0 + j) * 64 + cp];

        #pragma unroll
        for (int i = 0; i < 4; ++i) {
            // fp32 sequential sum, ascending window order == XLA reduce_window
            float ax = win[0].x, ay = win[0].y;
            #pragma unroll
            for (int j = 1; j < KW; ++j) { ax += win[j].x; ay += win[j].y; }
            f2v tf;
            tf.x = ax / 25.0f;                // IEEE f32 divide, matches sums/K
            tf.y = ay / 25.0f;
            const int row = (Rb + r0 + i) * 64 + cp;
            tb[row] = tf;                     // cached store (L2/L3 absorbs)

            const f2v xv = win[PADW];         // x[s]
            f2v so;                           // speculative: cond == true
            so.x = xv.x / (tf.x + 1e-8f);
            so.y = xv.y / (tf.y + 1e-8f);
            sv[row] = so;

            if (i & 1) { Sx_o.x += xv.x; Sx_o.y += xv.y; St_o.x += tf.x; St_o.y += tf.y; }
            else       { Sx_e.x += xv.x; Sx_e.y += xv.y; St_e.x += tf.x; St_e.y += tf.y; }
            Sx2.x += xv.x * xv.x;  Sx2.y += xv.y * xv.y;
            St2.x += tf.x * tf.x;  St2.y += tf.y * tf.y;
            Sxt.x += xv.x * tf.x;  Sxt.y += xv.y * tf.y;

            #pragma unroll
            for (int j = 0; j < KW - 1; ++j) win[j] = win[j + 1];
            if (i < 3) win[KW - 1] = stg[(r0 + i + KW) * 64 + cp];
        }

        if (c + 1 < CPB) commit(c + 1, cur ^ 1);
    }

    // ---- combine 8 row-groups deterministically (reuse stage LDS) ----
    __syncthreads();
    f2v* sr = (f2v*)stage;                    // 7 groups * 7 stats * 64 f2v
    if (rg > 0) {
        f2v* me = sr + (size_t)(rg - 1) * 7 * 64 + cp;
        me[0*64] = Sx_e; me[1*64] = Sx_o; me[2*64] = Sx2;
        me[3*64] = St_e; me[4*64] = St_o; me[5*64] = St2;
        me[6*64] = Sxt;
    }
    __syncthreads();
    if (rg == 0) {
        #pragma unroll
        for (int g = 0; g < 7; ++g) {
            const f2v* gp = sr + (size_t)g * 7 * 64 + cp;
            Sx_e.x += gp[0*64].x; Sx_e.y += gp[0*64].y;
            Sx_o.x += gp[1*64].x; Sx_o.y += gp[1*64].y;
            Sx2.x  += gp[2*64].x; Sx2.y  += gp[2*64].y;
            St_e.x += gp[3*64].x; St_e.y += gp[3*64].y;
            St_o.x += gp[4*64].x; St_o.y += gp[4*64].y;
            St2.x  += gp[5*64].x; St2.y  += gp[5*64].y;
            Sxt.x  += gp[6*64].x; Sxt.y  += gp[6*64].y;
        }
        const int series = b * CC + 2 * cp;   // float2-aligned
        float* sp = stats + (size_t)st * NSERIES + series;
        const size_t jstride = (size_t)NSTRIP * NSERIES;
        *(f2v*)(sp + 0 * jstride) = Sx_e;
        *(f2v*)(sp + 1 * jstride) = Sx_o;
        *(f2v*)(sp + 2 * jstride) = Sx2;
        *(f2v*)(sp + 3 * jstride) = St_e;
        *(f2v*)(sp + 4 * jstride) = St_o;
        *(f2v*)(sp + 5 * jstride) = St2;
        *(f2v*)(sp + 6 * jstride) = Sxt;
    }

    // ---- last block of this batch finalizes: cond + fixup ----
    __syncthreads();                          // drain all waves' stores
    if (tid == 0) {
        __threadfence();                      // release stats/trend/seasonal
        ticket_s = atomicAdd(&cnt[b], 1);
    }
    __syncthreads();
    if (ticket_s != NSTRIP - 1) return;

    __threadfence();                          // acquire others' stats
    if (tid < 448) {
        const int j = tid >> 6, c2 = tid & 63;
        const float* p = stats + (size_t)j * NSTRIP * NSERIES + b * CC + 2 * c2;
        f2v a = {0.f, 0.f};
        #pragma unroll
        for (int k = 0; k < NSTRIP; ++k) {
            const f2v v = *(const f2v*)(p + (size_t)k * NSERIES);
            a.x += v.x; a.y += v.y;
        }
        fin[j][2 * c2] = a.x; fin[j][2 * c2 + 1] = a.y;
    }
    if (tid == 0) nf = 0;
    __syncthreads();
    if (tid < 128) {
        const int ch = tid;
        const float Sx_eF = fin[0][ch], Sx_oF = fin[1][ch], Sx2F = fin[2][ch];
        const float St_eF = fin[3][ch], St_oF = fin[4][ch], St2F = fin[5][ch];
        const float SxtF = fin[6][ch];

        const float Sf = (float)SS;
        const float halfS = 0.5f * Sf;
        const float c_e = Sx_oF / Sf;         // opposite-parity mean at even n
        const float c_o = Sx_eF / Sf;
        const float sum_c = halfS * (c_e + c_o);
        const float sumsq_c = halfS * (c_e * c_e + c_o * c_o);

        const float Sw_e = 0.5f * Sx_eF - St_eF;
        const float Sw_o = 0.5f * Sx_oF - St_oF;
        const float Sw2 = 0.25f * Sx2F - SxtF + St2F;

        const float s1 = (Sw_e + Sw_o) + sum_c;
        const float q1 = Sw2 + 2.f * (c_e * Sw_e + c_o * Sw_o) + sumsq_c;
        const float var1 = (q1 - s1 * s1 / Sf) / (Sf - 1.f);
        const float s2 = 0.5f * (Sx_eF + Sx_oF) + sum_c;
        const float q2 = 0.25f * Sx2F + (c_e * Sx_eF + c_o * Sx_oF) + sumsq_c;
        const float var2 = (q2 - s2 * s2 / Sf) / (Sf - 1.f);
        const float Sa = (Sx_eF + Sx_oF) - (St_eF + St_oF);
        const float Sa2 = Sx2F - 2.f * SxtF + St2F;
        const float var3 = (Sa2 - Sa * Sa / Sf) / (Sf - 1.f);

        const float d_t = 1.f - var1 / (var2 + 1e-8f);
        const float d_s = 1.f - var1 / (var3 + 1e-8f);
        if (!(d_t > 0.5f || d_s > 0.5f))
            flist[atomicAdd(&nf, 1)] = ch;
    }
    __syncthreads();
    for (int fi = 0; fi < nf; ++fi) {         // additive fixup (cold path)
        const int ch = flist[fi];
        const float* xs = x + (size_t)b * SS * CC + ch;
        const float* ts = trend + (size_t)b * SS * CC + ch;
        float* so = seasonal + (size_t)b * SS * CC + ch;
        for (int s = tid; s < SS; s += 512)
            so[(size_t)s * CC] = xs[(size_t)s * CC] - ts[(size_t)s * CC];
    }
}

extern "C" void kernel_launch(void* const* d_in, const int* in_sizes, int n_in,
                              void* d_out, int out_size, void* d_ws, size_t ws_size,
                              hipStream_t stream) {
    const float* x = (const float*)d_in[0];
    float* out = (float*)d_out;
    float* trend = out;                               // output 0
    float* seasonal = out + (size_t)BB * SS * CC;     // output 1

    float* stats = (float*)d_ws;                      // 7*16*4096 floats = 1.75 MiB
    int* cnt = (int*)(stats + 7 * NSTRIP * NSERIES);  // 32 tickets

    hipMemsetAsync(cnt, 0, BB * sizeof(int), stream); // graph-safe
    kb_pass<<<dim3(BB * NSTRIP), dim3(512), 0, stream>>>(x, trend, seasonal,
                                                         stats, cnt);
}

// Round 16
// 39.854 us; speedup vs baseline: 2.4220x; 2.4220x over previous
//
#include <hip/hip_runtime.h>

#define SS 4096
#define CC 128
#define BB 32
#define KW 25
#define PADW 12
#define CH 64                   // rows per chunk
#define SROWS (CH + KW - 1)     // 88 staged rows per chunk
#define CPB 8                   // chunks per block (512 rows)
#define HC 64                   // channels per block (half of 128)
#define HCP 32                  // channel pairs per block
#define NSERIES (BB * CC)       // 4096
#define STAGE_F4 (SROWS * HC / 4)   // 1408 float4 = 22 KiB per buffer

typedef float f4v __attribute__((ext_vector_type(4)));
typedef float f2v __attribute__((ext_vector_type(2)));

// ---------------- KB: single full pass, channel-split ------------------------
// 512 blocks x 512 threads (2 blocks/CU: 45 KiB LDS, no VGPR cap). Block =
// (batch, 512-row quarter, 64-channel half); persistent over 8 chunks,
// double-buffered, halo LDS->LDS. Writes trend (bit-exact ascending chain) +
// SPECULATIVE seasonal=x/(t+eps) + 7 St-form stats.
__global__ __launch_bounds__(512)
void kb_pass(const float* __restrict__ x, float* __restrict__ trend,
             float* __restrict__ seasonal, float* __restrict__ stats) {
    __shared__ f4v stage[2][STAGE_F4];        // 45 KiB; tail reused for sred

    const int blk = blockIdx.x;               // 0..511
    const int b = blk >> 4;                   // batch
    const int q = (blk >> 1) & 7;             // quarter (512 rows)
    const int h = blk & 1;                    // channel half
    const int tid = threadIdx.x;
    const int cp = tid & 31;                  // channel pair within half
    const int rg = tid >> 5;                  // row group 0..15 (4 rows/chunk)
    const float* __restrict__ xbh = x + (size_t)b * SS * CC + h * HC;
    f2v* __restrict__ tb2 = (f2v*)(trend + (size_t)b * SS * CC);
    f2v* __restrict__ sv2 = (f2v*)(seasonal + (size_t)b * SS * CC);
    const int co = h * HCP + 0;               // f2v col base in full row

    // ---- prologue: stage rows q*512-12 .. +75 into buffer 0 ----
    {
        const int sbase = q * (CPB * CH) - PADW;
        #pragma unroll
        for (int t = 0; t < 3; ++t) {
            const int idx = t * 512 + tid;    // 0..1535
            if (idx < STAGE_F4) {
                const int srow = sbase + (idx >> 4);      // 16 f4 per row
                const int crow = srow < 0 ? 0 : (srow >= SS ? SS - 1 : srow);
                f4v v = *(const f4v*)(xbh + (size_t)crow * CC + ((idx & 15) << 2));
                if (srow < 0 || srow >= SS) v = (f4v){0.f, 0.f, 0.f, 0.f};
                stage[0][idx] = v;
            }
        }
    }

    f4v vals[2];
    auto issue = [&](int c) {                 // 64 new rows (staged 24..87)
        const int sbase = q * (CPB * CH) + c * CH - PADW;
        #pragma unroll
        for (int t = 0; t < 2; ++t) {
            const int nidx = t * 512 + tid;   // 0..1023
            const int srow = sbase + 24 + (nidx >> 4);
            const int crow = srow >= SS ? SS - 1 : srow;  // never <0 for c>=1
            vals[t] = *(const f4v*)(xbh + (size_t)crow * CC + ((nidx & 15) << 2));
        }
    };
    auto commit = [&](int c, int buf) {
        // halo: new staged rows 0..23 = old staged rows 64..87
        const f2v* src = (const f2v*)stage[buf ^ 1];
        f2v* dst = (f2v*)stage[buf];
        #pragma unroll
        for (int t = 0; t < 2; ++t) {
            const int hidx = t * 512 + tid;   // 0..1023; need 0..767
            if (hidx < 24 * HCP) dst[hidx] = src[CH * HCP + hidx];
        }
        const int sbase = q * (CPB * CH) + c * CH - PADW;
        #pragma unroll
        for (int t = 0; t < 2; ++t) {
            const int nidx = t * 512 + tid;
            const int srow = sbase + 24 + (nidx >> 4);
            f4v w = vals[t];
            if (srow >= SS) w = (f4v){0.f, 0.f, 0.f, 0.f};
            stage[buf][384 + nidx] = w;       // 24 rows * 16 f4 = 384
        }
    };

    f2v Sx_e = {0,0}, Sx_o = {0,0}, Sx2 = {0,0};
    f2v St_e = {0,0}, St_o = {0,0}, St2 = {0,0}, Sxt = {0,0};

    for (int c = 0; c < CPB; ++c) {
        __syncthreads();                      // stage[c&1] ready
        const int cur = c & 1;
        if (c + 1 < CPB) issue(c + 1);        // overlap loads with compute

        const int S0 = q * (CPB * CH) + c * CH;
        const int r0 = rg * 4;                // local row base (even)
        const f2v* stg = (const f2v*)stage[cur];

        f2v win[KW];
        #pragma unroll
        for (int j = 0; j < KW; ++j) win[j] = stg[(r0 + j) * HCP + cp];

        #pragma unroll
        for (int i = 0; i < 4; ++i) {
            // fp32 sequential sum, ascending window order == XLA reduce_window
            float ax = win[0].x, ay = win[0].y;
            #pragma unroll
            for (int j = 1; j < KW; ++j) { ax += win[j].x; ay += win[j].y; }
            f2v tf;
            tf.x = ax / 25.0f;                // IEEE f32 divide, matches sums/K
            tf.y = ay / 25.0f;
            const int row = (S0 + r0 + i) * 64 + co + cp;
            __builtin_nontemporal_store(tf, &tb2[row]);

            const f2v xv = win[PADW];         // x[s]
            f2v so;                           // speculative: cond == true
            so.x = xv.x / (tf.x + 1e-8f);
            so.y = xv.y / (tf.y + 1e-8f);
            __builtin_nontemporal_store(so, &sv2[row]);

            if (i & 1) { Sx_o.x += xv.x; Sx_o.y += xv.y; St_o.x += tf.x; St_o.y += tf.y; }
            else       { Sx_e.x += xv.x; Sx_e.y += xv.y; St_e.x += tf.x; St_e.y += tf.y; }
            Sx2.x += xv.x * xv.x;  Sx2.y += xv.y * xv.y;
            St2.x += tf.x * tf.x;  St2.y += tf.y * tf.y;
            Sxt.x += xv.x * tf.x;  Sxt.y += xv.y * tf.y;

            #pragma unroll
            for (int j = 0; j < KW - 1; ++j) win[j] = win[j + 1];
            if (i < 3) win[KW - 1] = stg[(r0 + i + KW) * HCP + cp];
        }

        if (c + 1 < CPB) commit(c + 1, cur ^ 1);
    }

    // ---- combine 16 row-groups deterministically (alias stage as sred) ----
    __syncthreads();                          // all stage reads done
    f2v* sr = (f2v*)stage;                    // 15 groups * 7 stats * 32 f2v
    if (rg > 0) {
        f2v* me = sr + (size_t)(rg - 1) * 7 * HCP + cp;
        me[0*HCP] = Sx_e; me[1*HCP] = Sx_o; me[2*HCP] = Sx2;
        me[3*HCP] = St_e; me[4*HCP] = St_o; me[5*HCP] = St2;
        me[6*HCP] = Sxt;
    }
    __syncthreads();
    if (rg == 0) {
        #pragma unroll
        for (int g = 0; g < 15; ++g) {
            const f2v* gp = sr + (size_t)g * 7 * HCP + cp;
            Sx_e.x += gp[0*HCP].x; Sx_e.y += gp[0*HCP].y;
            Sx_o.x += gp[1*HCP].x; Sx_o.y += gp[1*HCP].y;
            Sx2.x  += gp[2*HCP].x; Sx2.y  += gp[2*HCP].y;
            St_e.x += gp[3*HCP].x; St_e.y += gp[3*HCP].y;
            St_o.x += gp[4*HCP].x; St_o.y += gp[4*HCP].y;
            St2.x  += gp[5*HCP].x; St2.y  += gp[5*HCP].y;
            Sxt.x  += gp[6*HCP].x; Sxt.y  += gp[6*HCP].y;
        }
        const int series = b * CC + h * HC + 2 * cp;   // float2-aligned
        float* sp = stats + (size_t)q * NSERIES + series;
        const size_t jstride = (size_t)CPB * NSERIES;  // 8 quarter-partials
        *(f2v*)(sp + 0 * jstride) = Sx_e;
        *(f2v*)(sp + 1 * jstride) = Sx_o;
        *(f2v*)(sp + 2 * jstride) = Sx2;
        *(f2v*)(sp + 3 * jstride) = St_e;
        *(f2v*)(sp + 4 * jstride) = St_o;
        *(f2v*)(sp + 5 * jstride) = St2;
        *(f2v*)(sp + 6 * jstride) = Sxt;
    }
}

// ---------------- K2: fold partials -> cond; fix up cond-false series --------
__global__ __launch_bounds__(256)
void k2_finalize_fix(const float* __restrict__ stats, const float* __restrict__ x,
                     const float* __restrict__ trend, float* __restrict__ seasonal) {
    const int j = threadIdx.x >> 5;          // stat index 0..7 (7 used)
    const int sl = threadIdx.x & 31;
    const int series0 = blockIdx.x * 32;
    const size_t jstride = (size_t)CPB * NSERIES;

    __shared__ float red[32][8];
    __shared__ int nf;
    __shared__ int flist[32];
    if (threadIdx.x == 0) nf = 0;
    if (j < 7) {
        const float* p = stats + j * jstride + series0 + sl;
        float a = 0.f;
        #pragma unroll
        for (int k = 0; k < CPB; ++k) a += p[(size_t)k * NSERIES];
        red[sl][j] = a;
    }
    __syncthreads();
    if (threadIdx.x < 32) {
        const int me = threadIdx.x;
        const float Sx_e = red[me][0], Sx_o = red[me][1], Sx2 = red[me][2];
        const float St_e = red[me][3], St_o = red[me][4], St2 = red[me][5];
        const float Sxt = red[me][6];

        const float Sf = (float)SS;
        const float halfS = 0.5f * Sf;
        const float c_e = Sx_o / Sf;         // opposite-parity mean at even n
        const float c_o = Sx_e / Sf;
        const float sum_c = halfS * (c_e + c_o);
        const float sumsq_c = halfS * (c_e * c_e + c_o * c_o);

        const float Sw_e = 0.5f * Sx_e - St_e;
        const float Sw_o = 0.5f * Sx_o - St_o;
        const float Sw2 = 0.25f * Sx2 - Sxt + St2;

        // v1 = resid = w + c_p
        const float s1 = (Sw_e + Sw_o) + sum_c;
        const float q1 = Sw2 + 2.f * (c_e * Sw_e + c_o * Sw_o) + sumsq_c;
        const float var1 = (q1 - s1 * s1 / Sf) / (Sf - 1.f);
        // v2 = trend + resid = 0.5x + c_p
        const float s2 = 0.5f * (Sx_e + Sx_o) + sum_c;
        const float q2 = 0.25f * Sx2 + (c_e * Sx_e + c_o * Sx_o) + sumsq_c;
        const float var2 = (q2 - s2 * s2 / Sf) / (Sf - 1.f);
        // v3 = seasonal0 + resid = x - trend
        const float Sa = (Sx_e + Sx_o) - (St_e + St_o);
        const float Sa2 = Sx2 - 2.f * Sxt + St2;
        const float var3 = (Sa2 - Sa * Sa / Sf) / (Sf - 1.f);

        const float d_t = 1.f - var1 / (var2 + 1e-8f);
        const float d_s = 1.f - var1 / (var3 + 1e-8f);
        if (!(d_t > 0.5f || d_s > 0.5f)) {
            const int i = atomicAdd(&nf, 1);
            flist[i] = series0 + me;
        }
    }
    __syncthreads();
    for (int fi = 0; fi < nf; ++fi) {        // additive fixup (rare path)
        const int sr = flist[fi];
        const int b = sr >> 7, ch = sr & 127;
        const float* xs = x + (size_t)b * SS * CC + ch;
        const float* ts = trend + (size_t)b * SS * CC + ch;
        float* so = seasonal + (size_t)b * SS * CC + ch;
        for (int s = threadIdx.x; s < SS; s += 256)
            so[(size_t)s * CC] = xs[(size_t)s * CC] - ts[(size_t)s * CC];
    }
}

extern "C" void kernel_launch(void* const* d_in, const int* in_sizes, int n_in,
                              void* d_out, int out_size, void* d_ws, size_t ws_size,
                              hipStream_t stream) {
    const float* x = (const float*)d_in[0];
    float* out = (float*)d_out;
    float* trend = out;                               // output 0
    float* seasonal = out + (size_t)BB * SS * CC;     // output 1

    float* stats = (float*)d_ws;                      // 7*8*4096 floats ~ 896 KiB

    kb_pass<<<dim3(BB * 16), dim3(512), 0, stream>>>(x, trend, seasonal, stats);
    k2_finalize_fix<<<dim3(NSERIES / 32), dim3(256), 0, stream>>>(stats, x, trend, seasonal);
}